// Round 8
// baseline (203.509 us; speedup 1.0000x reference)
//
#include <hip/hip_runtime.h>

// Problem constants (match reference setup_inputs)
#define EDIM 128
#define NHEAD 4
#define NSEG 128
#define LOG2E 1.4426950408889634f

typedef float f32x8 __attribute__((ext_vector_type(8)));

// Round-7 post-mortem: atomics gone (dur 251->203); residual pass1 cost is
// (a) 16 ds_bpermute/quad reduce latency, (b) per-quad uniform batch load +
// branch, (c) thin TLP. This round: DPP-based 16-lane reduce (VALU only, no
// DS pipe), hoisted single-segment fast chunk (no batch reads in hot loop),
// and 2x waves (qpw=8).

#define DOT8(xv, wv)                                                     \
    fmaf((xv)[7], (wv)[7], fmaf((xv)[6], (wv)[6],                        \
    fmaf((xv)[5], (wv)[5], fmaf((xv)[4], (wv)[4],                        \
    fmaf((xv)[3], (wv)[3], fmaf((xv)[2], (wv)[2],                        \
    fmaf((xv)[1], (wv)[1], (xv)[0] * (wv)[0])))))))

// Sum across each 16-lane row via DPP: xor1 (quad_perm [1,0,3,2] = 0xB1),
// xor2 (quad_perm [2,3,0,1] = 0x4E), row_ror:4 (0x124), row_ror:8 (0x128).
// After xor1+xor2 each lane holds its 4-lane quad sum (quad-uniform), so the
// two rotations accumulate all four quad sums -> every lane = row total.
__device__ __forceinline__ float dpp_add16(float v) {
    v += __int_as_float(__builtin_amdgcn_update_dpp(
        0, __float_as_int(v), 0xB1, 0xF, 0xF, true));
    v += __int_as_float(__builtin_amdgcn_update_dpp(
        0, __float_as_int(v), 0x4E, 0xF, 0xF, true));
    v += __int_as_float(__builtin_amdgcn_update_dpp(
        0, __float_as_int(v), 0x124, 0xF, 0xF, true));
    v += __int_as_float(__builtin_amdgcn_update_dpp(
        0, __float_as_int(v), 0x128, 0xF, 0xF, true));
    return v;
}

// butterfly across the 4 groups (bits 4..5 of lane) — cold path only
#define REDG(v)  do { v += __shfl_xor(v, 16, 64); v += __shfl_xor(v, 32, 64); } while (0)

// Cross-group reduce the wave's accumulators and store them (plain stores,
// no atomics) into slot (wave*2 + min(nflushed,1)), tagged with `seg`.
#define FLUSH_STORE(seg) do {                                            \
    float t0 = s0, t1 = s1, t2 = s2, t3 = s3;                            \
    REDG(t0); REDG(t1); REDG(t2); REDG(t3);                              \
    f32x8 r0 = a0, r1 = a1, r2 = a2, r3 = a3;                            \
    _Pragma("unroll")                                                    \
    for (int j = 0; j < 8; ++j) {                                        \
        float u0 = r0[j]; REDG(u0); r0[j] = u0;                          \
        float u1 = r1[j]; REDG(u1); r1[j] = u1;                          \
        float u2 = r2[j]; REDG(u2); r2[j] = u2;                          \
        float u3 = r3[j]; REDG(u3); r3[j] = u3;                          \
    }                                                                    \
    f32x8 rv = (g == 0) ? r0 : ((g == 1) ? r1 : ((g == 2) ? r2 : r3));   \
    const size_t ent_ = (size_t)wave * 2 + (nflushed < 1 ? 0 : 1);       \
    *reinterpret_cast<f32x8*>(pouth + ent_ * 512 + g * EDIM + 8 * c) = rv; \
    if (lane == 0) {                                                     \
        psum[ent_ * 4 + 0] = t0; psum[ent_ * 4 + 1] = t1;                \
        psum[ent_ * 4 + 2] = t2; psum[ent_ * 4 + 3] = t3;                \
        pseg[ent_] = (seg);                                              \
    }                                                                    \
    nflushed++;                                                          \
    a0 = Z8; a1 = Z8; a2 = Z8; a3 = Z8;                                  \
    s0 = 0.f; s1 = 0.f; s2 = 0.f; s3 = 0.f;                              \
} while (0)

__global__ __launch_bounds__(256) void attn_agg_pass1(
    const float* __restrict__ x, const float* __restrict__ w,
    const int* __restrict__ batch,
    float* __restrict__ pouth,      // [nent][4*128] partial e*x
    float* __restrict__ psum,       // [nent][4]     partial e sums
    int*   __restrict__ pseg,       // [nent]        segment tag (-1 unused)
    int n, int qpw)
{
    const int tid  = blockIdx.x * blockDim.x + threadIdx.x;
    const int wave = tid >> 6;
    const int lane = threadIdx.x & 63;
    const int g    = lane >> 4;     // cell within quad
    const int c    = lane & 15;     // dim chunk (8 floats)

    const int nquads = (n + 3) >> 2;
    const int q0 = wave * qpw;
    if (q0 >= nquads) {             // idle wave: mark both slots unused
        if (lane == 0) { pseg[(size_t)wave * 2] = -1; pseg[(size_t)wave * 2 + 1] = -1; }
        return;
    }
    const int q1 = min(q0 + qpw, nquads);

    // weights for this lane's 8 dims, all 4 heads — SSA vector values
    const float* wp = w + 8 * c;
    const f32x8 w0 = *reinterpret_cast<const f32x8*>(wp + 0 * EDIM);
    const f32x8 w1 = *reinterpret_cast<const f32x8*>(wp + 1 * EDIM);
    const f32x8 w2 = *reinterpret_cast<const f32x8*>(wp + 2 * EDIM);
    const f32x8 w3 = *reinterpret_cast<const f32x8*>(wp + 3 * EDIM);

    const f32x8 Z8 = {0.f, 0.f, 0.f, 0.f, 0.f, 0.f, 0.f, 0.f};
    f32x8 a0 = Z8, a1 = Z8, a2 = Z8, a3 = Z8;
    float s0 = 0.f, s1 = 0.f, s2 = 0.f, s3 = 0.f;
    int nflushed = 0;

    const int cellN = min(q1 * 4, n);
    int cur_b = __builtin_amdgcn_readfirstlane(batch[q0 * 4]);
    const int last_b = __builtin_amdgcn_readfirstlane(batch[cellN - 1]);

    if (cur_b == last_b && q1 * 4 <= n) {
        // ---- hot chunk (~98% of waves): whole chunk one segment, no batch
        // reads, no clamps, branch-free inner loop ----
        const float* xp = x + (size_t)(q0 * 4 + g) * EDIM + 8 * c;
        for (int q = q0; q < q1; ++q) {
            const f32x8 xv = *reinterpret_cast<const f32x8*>(xp);
            xp += 4 * EDIM;

            float p0 = DOT8(xv, w0);
            float p1 = DOT8(xv, w1);
            float p2 = DOT8(xv, w2);
            float p3 = DOT8(xv, w3);
            p0 = dpp_add16(p0); p1 = dpp_add16(p1);
            p2 = dpp_add16(p2); p3 = dpp_add16(p3);

            const float e0 = __builtin_exp2f(p0 * LOG2E);
            const float e1 = __builtin_exp2f(p1 * LOG2E);
            const float e2 = __builtin_exp2f(p2 * LOG2E);
            const float e3 = __builtin_exp2f(p3 * LOG2E);

            s0 += e0; s1 += e1; s2 += e2; s3 += e3;
            a0 += xv * e0; a1 += xv * e1; a2 += xv * e2; a3 += xv * e3;
        }
    } else {
        // ---- generic chunk (~2% of waves): per-quad segment handling ----
        for (int q = q0; q < q1; ++q) {
            const int cell = q * 4 + g;
            const int row  = min(cell, n - 1);
            const f32x8 xv = *reinterpret_cast<const f32x8*>(
                x + (size_t)row * EDIM + 8 * c);

            float p0 = DOT8(xv, w0);
            float p1 = DOT8(xv, w1);
            float p2 = DOT8(xv, w2);
            float p3 = DOT8(xv, w3);
            p0 = dpp_add16(p0); p1 = dpp_add16(p1);
            p2 = dpp_add16(p2); p3 = dpp_add16(p3);

            const float e0 = __builtin_exp2f(p0 * LOG2E);
            const float e1 = __builtin_exp2f(p1 * LOG2E);
            const float e2 = __builtin_exp2f(p2 * LOG2E);
            const float e3 = __builtin_exp2f(p3 * LOG2E);

            const bool full = (q * 4 + 3 < n);
            const int  b3   = __builtin_amdgcn_readfirstlane(batch[min(q * 4 + 3, n - 1)]);

            if (full && b3 == cur_b) {
                s0 += e0; s1 += e1; s2 += e2; s3 += e3;
                a0 += xv * e0; a1 += xv * e1; a2 += xv * e2; a3 += xv * e3;
            } else {
                // boundary/tail quad: masked accumulate old seg, flush, new seg
                const int my_b = (cell < n) ? batch[cell] : -2;   // per-group id
                const bool m1 = (my_b == cur_b);
                const float f1 = m1 ? 1.f : 0.f;
                s0 += e0 * f1; s1 += e1 * f1; s2 += e2 * f1; s3 += e3 * f1;
                a0 += xv * (e0 * f1); a1 += xv * (e1 * f1);
                a2 += xv * (e2 * f1); a3 += xv * (e3 * f1);

                FLUSH_STORE(cur_b);
                cur_b = b3;

                const float f2 = (!m1 && my_b == cur_b) ? 1.f : 0.f;
                s0 += e0 * f2; s1 += e1 * f2; s2 += e2 * f2; s3 += e3 * f2;
                a0 += xv * (e0 * f2); a1 += xv * (e1 * f2);
                a2 += xv * (e2 * f2); a3 += xv * (e3 * f2);
            }
        }
    }

    FLUSH_STORE(cur_b);
    if (lane == 0 && nflushed < 2) pseg[(size_t)wave * 2 + 1] = -1;
}

// Pass 2: one block per segment. Build LDS match-list over slot tags, gather
// partials, then out[b,d] = 0.25 * sum_h outh[b,h,d] / s[b,h].
__global__ __launch_bounds__(512) void attn_agg_finish(
    const float* __restrict__ pouth, const float* __restrict__ psum,
    const int* __restrict__ pseg, float* __restrict__ out, int nent)
{
    const int b = blockIdx.x;            // segment id
    const int t = threadIdx.x;           // 0..511
    const int h = t >> 7, d = t & (EDIM - 1);

    __shared__ int matches[1024];
    __shared__ int nmatch;
    __shared__ float hacc[NHEAD][EDIM];
    if (t == 0) nmatch = 0;
    __syncthreads();

    for (int i = t; i < nent; i += 512) {
        if (pseg[i] == b) {
            int p = atomicAdd(&nmatch, 1);   // LDS atomic — cheap
            if (p < 1024) matches[p] = i;
        }
    }
    __syncthreads();

    float acc = 0.f, sh = 0.f;
    const int nm = min(nmatch, 1024);
    for (int k = 0; k < nm; ++k) {
        const int i = matches[k];
        acc += pouth[(size_t)i * 512 + t];   // t == h*128+d, coalesced
        sh  += psum[(size_t)i * 4 + h];
    }
    hacc[h][d] = (sh > 0.f) ? (acc / sh) : 0.f;
    __syncthreads();

    if (h == 0)
        out[b * EDIM + d] = 0.25f *
            (hacc[0][d] + hacc[1][d] + hacc[2][d] + hacc[3][d]);
}

extern "C" void kernel_launch(void* const* d_in, const int* in_sizes, int n_in,
                              void* d_out, int out_size, void* d_ws, size_t ws_size,
                              hipStream_t stream) {
    const float* x     = (const float*)d_in[0];   // [N, 128] f32
    const float* w     = (const float*)d_in[1];   // [4, 128] f32
    const int*   batch = (const int*)d_in[2];     // [N] int (sorted)
    float* out = (float*)d_out;                   // [128, 128] f32

    const int n = in_sizes[0] / EDIM;             // 250000
    const int nquads = (n + 3) >> 2;              // 62500

    // target 8192 waves (qpw=8) for TLP; shrink if workspace is small
    const size_t per_ent = 512 * 4 + 4 * 4 + 4;   // pouth + psum + pseg bytes
    int W = 8192;
    const size_t max_ent = ws_size / per_ent;
    if ((size_t)W * 2 + 16 > max_ent) W = (int)(max_ent / 2) - 8;
    if (W < 64) W = 64;

    const int qpw      = (nquads + W - 1) / W;    // 8 @ W=8192
    const int nw       = (nquads + qpw - 1) / qpw;
    const int blocks1  = (nw + 3) / 4;
    const int launched = blocks1 * 4;
    const int nent     = launched * 2;

    float* pouth = (float*)d_ws;                  // [nent][512]
    float* psum  = pouth + (size_t)nent * 512;    // [nent][4]
    int*   pseg  = (int*)(psum + (size_t)nent * 4); // [nent]

    attn_agg_pass1<<<blocks1, 256, 0, stream>>>(x, w, batch, pouth, psum, pseg, n, qpw);
    attn_agg_finish<<<NSEG, 512, 0, stream>>>(pouth, psum, pseg, out, nent);
}